// Round 8
// baseline (14.807 us; speedup 1.0000x reference)
//
#include <hip/hip_runtime.h>
#include <math.h>

// Problem constants
#define BATCH   32
#define DIMN    96
#define KCOMP   64
#define NUM_IN  (DIMN*DIMN)   // 9216
#define NUM_OUT (DIMN*DIMN)   // 9216

// ws layout (floats):
//   Yp[32][8][64] @ 0      : partial projections per (b, a-twelfth)
//   F2[64][96]    @ 16384  : out-dim-0 factor, weights folded in
//   F3[64][96]    @ 22528  : out-dim-1 factor
#define YP_OFF 0
#define F2_OFF 16384
#define F3_OFF 22528

// Math (fp32 throughout; identical formulas to R5-R7 which passed at 0.0625):
//   f_dim[k][i] = exp(-(i/95 - mu[k,dim])^2 * 0.5*exp(-log_var[k,dim]))
//   Y[b,k]      = sum_a f0[k][a] * sum_e x[b,a,e] * f1[k][e]
//   out[b,c,d]  = bias[c,d] + sum_k (w[k]*Y[b,k]) * f2[k][c] * f3[k][d]

// ---------------------------------------------------------------------------
// Kernel A (unchanged from R7): 280 blocks x 512 threads.
//  - Blocks 0..255: projection partials. Block = (b = bid>>3, aq = bid&7),
//    12 a-rows staged in LDS, f1 table in LDS; wave w: row-group rg = w>>1,
//    e-half eh = w&1, lane = k. Main loop pure LDS.
//  - Blocks 256..279: build F2/F3 tables into ws.
// ---------------------------------------------------------------------------
__global__ __launch_bounds__(512) void kA(const float* __restrict__ x,
                                          const float* __restrict__ mus,
                                          const float* __restrict__ log_vars,
                                          const float* __restrict__ weights,
                                          float* __restrict__ ws) {
    const int tid = threadIdx.x;
    const int bid = blockIdx.x;

    if (bid >= 256) {                       // ---- table blocks ----
        int idx = (bid - 256) * 512 + tid;  // 0..12287
        int half = idx >= (KCOMP * DIMN);
        int t = idx - half * (KCOMP * DIMN);
        int k = t / DIMN;
        int i = t - k * DIMN;
        int dim = 2 + half;
        float mu = mus[k * 4 + dim];
        float rv = 0.5f * expf(-log_vars[k * 4 + dim]);
        float g  = (float)i * (1.0f / 95.0f) - mu;
        float v  = expf(-(g * g) * rv);
        if (!half) v *= weights[k];         // fold weights into F2
        ws[(half ? F3_OFF : F2_OFF) + t] = v;
        return;
    }

    __shared__ float f1[DIMN * KCOMP];      // [e][k], 24 KB
    __shared__ float xs[12 * DIMN];         // 12 staged a-rows, 4.5 KB
    __shared__ float part[8][KCOMP];        // 2 KB

    const int b  = bid >> 3;
    const int aq = bid & 7;

    // stage this block's 12 x-rows: 288 coalesced float4 loads
    {
        const float4* xg = (const float4*)(x + b * NUM_IN + aq * 12 * DIMN);
        if (tid < 288) ((float4*)xs)[tid] = xg[tid];
    }
    // build f1 (input dim 1): k = tid&63 is loop-invariant
    {
        const int k  = tid & 63;
        const int e0 = tid >> 6;            // 0..7
        float mu = mus[k * 4 + 1];
        float rv = 0.5f * expf(-log_vars[k * 4 + 1]);
        #pragma unroll
        for (int j = 0; j < 12; ++j) {
            int e = e0 + j * 8;
            float t = (float)e * (1.0f / 95.0f) - mu;
            f1[e * 64 + k] = expf(-(t * t) * rv);
        }
    }
    __syncthreads();

    const int w    = tid >> 6;              // 0..7
    const int lane = tid & 63;              // = k
    const int rg   = w >> 1;                // 0..3
    const int eh   = w & 1;                 // e-half
    const int a0   = aq * 12 + rg * 3;

    const float* xr = xs + (rg * 3) * DIMN; // this wave's 3 rows (LDS)

    float acc0 = 0.0f, acc1 = 0.0f, acc2 = 0.0f;
    #pragma unroll 4
    for (int e4 = eh * 12; e4 < eh * 12 + 12; ++e4) {
        float f10 = f1[(e4 * 4 + 0) * 64 + lane];
        float f11 = f1[(e4 * 4 + 1) * 64 + lane];
        float f12 = f1[(e4 * 4 + 2) * 64 + lane];
        float f13 = f1[(e4 * 4 + 3) * 64 + lane];
        const float4 x0 = *(const float4*)(xr + 0 * DIMN + e4 * 4);  // LDS broadcast
        const float4 x1 = *(const float4*)(xr + 1 * DIMN + e4 * 4);
        const float4 x2 = *(const float4*)(xr + 2 * DIMN + e4 * 4);
        acc0 = fmaf(x0.x, f10, acc0); acc0 = fmaf(x0.y, f11, acc0);
        acc0 = fmaf(x0.z, f12, acc0); acc0 = fmaf(x0.w, f13, acc0);
        acc1 = fmaf(x1.x, f10, acc1); acc1 = fmaf(x1.y, f11, acc1);
        acc1 = fmaf(x1.z, f12, acc1); acc1 = fmaf(x1.w, f13, acc1);
        acc2 = fmaf(x2.x, f10, acc2); acc2 = fmaf(x2.y, f11, acc2);
        acc2 = fmaf(x2.z, f12, acc2); acc2 = fmaf(x2.w, f13, acc2);
    }

    // fold f0 (input dim 0) for this lane's k over the 3 a-rows
    float mu0 = mus[lane * 4 + 0];
    float rv0 = 0.5f * expf(-log_vars[lane * 4 + 0]);
    float g0 = (float)(a0 + 0) * (1.0f / 95.0f) - mu0;
    float g1 = (float)(a0 + 1) * (1.0f / 95.0f) - mu0;
    float g2 = (float)(a0 + 2) * (1.0f / 95.0f) - mu0;
    float yp = expf(-(g0 * g0) * rv0) * acc0
             + expf(-(g1 * g1) * rv0) * acc1
             + expf(-(g2 * g2) * rv0) * acc2;

    part[w][lane] = yp;
    __syncthreads();
    if (tid < KCOMP) {
        float s = 0.0f;
        #pragma unroll
        for (int q = 0; q < 8; ++q) s += part[q][tid];
        ws[YP_OFF + (b * 8 + aq) * KCOMP + tid] = s;
    }
}

// ---------------------------------------------------------------------------
// Kernel B v3: 256 blocks (b = bid>>3, oc = bid&7) x 288 threads. No exps.
//  - Ysum[k] = sum_q Yp[b][q][k] (64 threads), G1 <- F3 staged as float4.
//  - YG0[k][cl] = Ysum[k] * F2[k][oc*12+cl]  (weights pre-folded in F2).
//  - Main: thread = (kq = tid/72, ctile = (tid%72)/24, dq = tid%24);
//    4c x 4d x 16k: per k one b128 (G1) + one b128 (YG0 c-tile) -> 16 FMA.
//  - pacc stride 20 floats (bank-spread, 16B-aligned); combine thread =
//    (sub = tid/72, rem = tid%72): float4 partial reads, float4 bias+store.
// ---------------------------------------------------------------------------
__global__ __launch_bounds__(288) void kB(const float* __restrict__ ws,
                                          const float* __restrict__ bias,
                                          float* __restrict__ out) {
    __shared__ float G1[KCOMP * DIMN];      // [k][d], 24 KB
    __shared__ float YG0[KCOMP * 12];       // [k][cl], 3 KB
    __shared__ float Ysum[KCOMP];
    __shared__ float pacc[4 * 72 * 20];     // 22.5 KB

    const int tid = threadIdx.x;
    const int bid = blockIdx.x;
    const int b   = bid >> 3;
    const int oc  = bid & 7;

    // stage G1 <- F3 (global, L2-hot) as float4
    {
        const float4* F3g = (const float4*)(ws + F3_OFF);
        float4* G1v = (float4*)G1;
        #pragma unroll
        for (int i = tid; i < (KCOMP * DIMN) / 4; i += 288) G1v[i] = F3g[i];
    }
    // Ysum[k] = sum_q Yp[b][q][k]
    if (tid < KCOMP) {
        const float* Ypb = ws + YP_OFF + b * 8 * KCOMP;
        float s = 0.0f;
        #pragma unroll
        for (int q = 0; q < 8; ++q) s += Ypb[q * KCOMP + tid];
        Ysum[tid] = s;
    }
    __syncthreads();

    // YG0[k][cl] = Ysum[k] * F2[k][oc*12+cl]
    {
        const float* F2g = ws + F2_OFF;
        for (int idx = tid; idx < KCOMP * 12; idx += 288) {
            int k  = idx / 12;
            int cl = idx - k * 12;
            YG0[idx] = Ysum[k] * F2g[k * DIMN + oc * 12 + cl];
        }
    }
    __syncthreads();

    // main rank-64 update: 4c x 4d per thread, k split 4 ways
    {
        const int kq    = tid / 72;         // 0..3
        const int r     = tid - kq * 72;    // 0..71
        const int ctile = r / 24;           // 0..2
        const int dq    = r - ctile * 24;   // 0..23
        const int k0    = kq * 16;

        float acc[4][4];
        #pragma unroll
        for (int i = 0; i < 4; ++i)
            #pragma unroll
            for (int j = 0; j < 4; ++j) acc[i][j] = 0.0f;

        #pragma unroll 8
        for (int kk = 0; kk < 16; ++kk) {
            int k = k0 + kk;
            const float4 g = *(const float4*)&G1[k * DIMN + dq * 4];
            const float4 y = *(const float4*)&YG0[k * 12 + ctile * 4];
            acc[0][0] = fmaf(y.x, g.x, acc[0][0]); acc[0][1] = fmaf(y.x, g.y, acc[0][1]);
            acc[0][2] = fmaf(y.x, g.z, acc[0][2]); acc[0][3] = fmaf(y.x, g.w, acc[0][3]);
            acc[1][0] = fmaf(y.y, g.x, acc[1][0]); acc[1][1] = fmaf(y.y, g.y, acc[1][1]);
            acc[1][2] = fmaf(y.y, g.z, acc[1][2]); acc[1][3] = fmaf(y.y, g.w, acc[1][3]);
            acc[2][0] = fmaf(y.z, g.x, acc[2][0]); acc[2][1] = fmaf(y.z, g.y, acc[2][1]);
            acc[2][2] = fmaf(y.z, g.z, acc[2][2]); acc[2][3] = fmaf(y.z, g.w, acc[2][3]);
            acc[3][0] = fmaf(y.w, g.x, acc[3][0]); acc[3][1] = fmaf(y.w, g.y, acc[3][1]);
            acc[3][2] = fmaf(y.w, g.z, acc[3][2]); acc[3][3] = fmaf(y.w, g.w, acc[3][3]);
        }
        float* pa = &pacc[(kq * 72 + r) * 20];
        #pragma unroll
        for (int ci = 0; ci < 4; ++ci)
            *(float4*)&pa[ci * 4] = make_float4(acc[ci][0], acc[ci][1],
                                                acc[ci][2], acc[ci][3]);
    }
    __syncthreads();

    // combine 4 k-partials + bias + store: thread = (sub = tid/72, rem)
    {
        const int sub = tid / 72;           // 0..3 -> c within tile
        const int rem = tid - sub * 72;     // 0..71
        const int ct2 = rem / 24;
        const int dq2 = rem - ct2 * 24;
        const int c   = oc * 12 + ct2 * 4 + sub;
        const int d0  = dq2 * 4;

        float4 s = make_float4(0.f, 0.f, 0.f, 0.f);
        #pragma unroll
        for (int kq = 0; kq < 4; ++kq) {
            const float4 p = *(const float4*)&pacc[(kq * 72 + rem) * 20 + sub * 4];
            s.x += p.x; s.y += p.y; s.z += p.z; s.w += p.w;
        }
        const int o = c * DIMN + d0;
        const float4 bs = *(const float4*)&bias[o];
        *(float4*)&out[b * NUM_OUT + o] =
            make_float4(s.x + bs.x, s.y + bs.y, s.z + bs.z, s.w + bs.w);
    }
}

// ---------------------------------------------------------------------------
extern "C" void kernel_launch(void* const* d_in, const int* in_sizes, int n_in,
                              void* d_out, int out_size, void* d_ws, size_t ws_size,
                              hipStream_t stream) {
    const float* x        = (const float*)d_in[0];   // (32, 96, 96)
    const float* mus      = (const float*)d_in[1];   // (64, 4)
    const float* log_vars = (const float*)d_in[2];   // (64, 4)
    const float* weights  = (const float*)d_in[3];   // (64,)
    const float* bias     = (const float*)d_in[4];   // (9216,)
    float* out = (float*)d_out;                      // (32, 96, 96)
    float* ws  = (float*)d_ws;

    kA<<<280, 512, 0, stream>>>(x, mus, log_vars, weights, ws);
    kB<<<256, 288, 0, stream>>>(ws, bias, out);
}

// Round 9
// 14.141 us; speedup vs baseline: 1.0470x; 1.0470x over previous
//
#include <hip/hip_runtime.h>
#include <math.h>

// Problem constants
#define BATCH   32
#define DIMN    96
#define KCOMP   64
#define NUM_IN  (DIMN*DIMN)   // 9216
#define NUM_OUT (DIMN*DIMN)   // 9216

// ws layout (floats):
//   Yp[32][8][64] @ 0      : partial projections per (b, a-twelfth)
//   F2[64][96]    @ 16384  : out-dim-0 factor, weights folded in
//   F3[64][96]    @ 22528  : out-dim-1 factor
#define YP_OFF 0
#define F2_OFF 16384
#define F3_OFF 22528

// Math (fp32 throughout; identical formulas to R5-R8 which passed at 0.0625):
//   f_dim[k][i] = exp(-(i/95 - mu[k,dim])^2 * 0.5*exp(-log_var[k,dim]))
//   Y[b,k]      = sum_a f0[k][a] * sum_e x[b,a,e] * f1[k][e]
//   out[b,c,d]  = bias[c,d] + sum_k (w[k]*Y[b,k]) * f2[k][c] * f3[k][d]

// ---------------------------------------------------------------------------
// Kernel A (unchanged from R7 — known-good at 14.0): 280 blocks x 512 threads.
//  - Blocks 0..255: projection partials. Block = (b = bid>>3, aq = bid&7),
//    12 a-rows staged in LDS, f1 table in LDS; wave w: row-group rg = w>>1,
//    e-half eh = w&1, lane = k. Main loop pure LDS.
//  - Blocks 256..279: build F2/F3 tables into ws.
// ---------------------------------------------------------------------------
__global__ __launch_bounds__(512) void kA(const float* __restrict__ x,
                                          const float* __restrict__ mus,
                                          const float* __restrict__ log_vars,
                                          const float* __restrict__ weights,
                                          float* __restrict__ ws) {
    const int tid = threadIdx.x;
    const int bid = blockIdx.x;

    if (bid >= 256) {                       // ---- table blocks ----
        int idx = (bid - 256) * 512 + tid;  // 0..12287
        int half = idx >= (KCOMP * DIMN);
        int t = idx - half * (KCOMP * DIMN);
        int k = t / DIMN;
        int i = t - k * DIMN;
        int dim = 2 + half;
        float mu = mus[k * 4 + dim];
        float rv = 0.5f * expf(-log_vars[k * 4 + dim]);
        float g  = (float)i * (1.0f / 95.0f) - mu;
        float v  = expf(-(g * g) * rv);
        if (!half) v *= weights[k];         // fold weights into F2
        ws[(half ? F3_OFF : F2_OFF) + t] = v;
        return;
    }

    __shared__ float f1[DIMN * KCOMP];      // [e][k], 24 KB
    __shared__ float xs[12 * DIMN];         // 12 staged a-rows, 4.5 KB
    __shared__ float part[8][KCOMP];        // 2 KB

    const int b  = bid >> 3;
    const int aq = bid & 7;

    // stage this block's 12 x-rows: 288 coalesced float4 loads
    {
        const float4* xg = (const float4*)(x + b * NUM_IN + aq * 12 * DIMN);
        if (tid < 288) ((float4*)xs)[tid] = xg[tid];
    }
    // build f1 (input dim 1): k = tid&63 is loop-invariant
    {
        const int k  = tid & 63;
        const int e0 = tid >> 6;            // 0..7
        float mu = mus[k * 4 + 1];
        float rv = 0.5f * expf(-log_vars[k * 4 + 1]);
        #pragma unroll
        for (int j = 0; j < 12; ++j) {
            int e = e0 + j * 8;
            float t = (float)e * (1.0f / 95.0f) - mu;
            f1[e * 64 + k] = expf(-(t * t) * rv);
        }
    }
    __syncthreads();

    const int w    = tid >> 6;              // 0..7
    const int lane = tid & 63;              // = k
    const int rg   = w >> 1;                // 0..3
    const int eh   = w & 1;                 // e-half
    const int a0   = aq * 12 + rg * 3;

    const float* xr = xs + (rg * 3) * DIMN; // this wave's 3 rows (LDS)

    float acc0 = 0.0f, acc1 = 0.0f, acc2 = 0.0f;
    #pragma unroll 4
    for (int e4 = eh * 12; e4 < eh * 12 + 12; ++e4) {
        float f10 = f1[(e4 * 4 + 0) * 64 + lane];
        float f11 = f1[(e4 * 4 + 1) * 64 + lane];
        float f12 = f1[(e4 * 4 + 2) * 64 + lane];
        float f13 = f1[(e4 * 4 + 3) * 64 + lane];
        const float4 x0 = *(const float4*)(xr + 0 * DIMN + e4 * 4);  // LDS broadcast
        const float4 x1 = *(const float4*)(xr + 1 * DIMN + e4 * 4);
        const float4 x2 = *(const float4*)(xr + 2 * DIMN + e4 * 4);
        acc0 = fmaf(x0.x, f10, acc0); acc0 = fmaf(x0.y, f11, acc0);
        acc0 = fmaf(x0.z, f12, acc0); acc0 = fmaf(x0.w, f13, acc0);
        acc1 = fmaf(x1.x, f10, acc1); acc1 = fmaf(x1.y, f11, acc1);
        acc1 = fmaf(x1.z, f12, acc1); acc1 = fmaf(x1.w, f13, acc1);
        acc2 = fmaf(x2.x, f10, acc2); acc2 = fmaf(x2.y, f11, acc2);
        acc2 = fmaf(x2.z, f12, acc2); acc2 = fmaf(x2.w, f13, acc2);
    }

    // fold f0 (input dim 0) for this lane's k over the 3 a-rows
    float mu0 = mus[lane * 4 + 0];
    float rv0 = 0.5f * expf(-log_vars[lane * 4 + 0]);
    float g0 = (float)(a0 + 0) * (1.0f / 95.0f) - mu0;
    float g1 = (float)(a0 + 1) * (1.0f / 95.0f) - mu0;
    float g2 = (float)(a0 + 2) * (1.0f / 95.0f) - mu0;
    float yp = expf(-(g0 * g0) * rv0) * acc0
             + expf(-(g1 * g1) * rv0) * acc1
             + expf(-(g2 * g2) * rv0) * acc2;

    part[w][lane] = yp;
    __syncthreads();
    if (tid < KCOMP) {
        float s = 0.0f;
        #pragma unroll
        for (int q = 0; q < 8; ++q) s += part[q][tid];
        ws[YP_OFF + (b * 8 + aq) * KCOMP + tid] = s;
    }
}

// ---------------------------------------------------------------------------
// Kernel B v4: 256 blocks (b = bid>>3, oc = bid&7) x 576 threads (9 waves).
//  - Ysum[k] = sum_q Yp[b][q][k]; G1 <- F3 staged as float4.
//  - YG0 TRANSPOSED: [cl][k] (12 x 64) = Ysum[k] * F2[k][oc*12+cl].
//  - Main: thread = (kq = tid/144, p = c-pair 0..5, dq = d-quad 0..23).
//    y-values (2 c x 16 k, contiguous in [cl][k]) preloaded via 8 b128;
//    loop: 16 x { b128 G1 read -> 8 FMA }. 24 LDS instr/thread vs v2's 32.
//  - pacc stride 9 floats (v2's known-good conflict-free pattern).
// ---------------------------------------------------------------------------
__global__ __launch_bounds__(576) void kB(const float* __restrict__ ws,
                                          const float* __restrict__ bias,
                                          float* __restrict__ out) {
    __shared__ float G1[KCOMP * DIMN];      // [k][d], 24 KB
    __shared__ float YG0[12 * KCOMP];       // [cl][k], 3 KB
    __shared__ float Ysum[KCOMP];
    __shared__ float pacc[4 * 144 * 9];     // 20.25 KB

    const int tid = threadIdx.x;
    const int bid = blockIdx.x;
    const int b   = bid >> 3;
    const int oc  = bid & 7;

    // stage G1 <- F3 (global, L2-hot) as float4
    {
        const float4* F3g = (const float4*)(ws + F3_OFF);
        float4* G1v = (float4*)G1;
        #pragma unroll
        for (int i = tid; i < (KCOMP * DIMN) / 4; i += 576) G1v[i] = F3g[i];
    }
    // Ysum[k] = sum_q Yp[b][q][k]
    if (tid < KCOMP) {
        const float* Ypb = ws + YP_OFF + b * 8 * KCOMP;
        float s = 0.0f;
        #pragma unroll
        for (int q = 0; q < 8; ++q) s += Ypb[q * KCOMP + tid];
        Ysum[tid] = s;
    }
    __syncthreads();

    // YG0[cl][k] = Ysum[k] * F2[k][oc*12+cl]   (768 elements, k = idx&63)
    {
        const float* F2g = ws + F2_OFF;
        for (int idx = tid; idx < 12 * KCOMP; idx += 576) {
            int k  = idx & 63;
            int cl = idx >> 6;
            YG0[idx] = Ysum[k] * F2g[k * DIMN + oc * 12 + cl];
        }
    }
    __syncthreads();

    // main rank-64 update: 2c x 4d per thread, k split 4 ways, y preloaded
    {
        const int kq = tid / 144;           // 0..3
        const int r  = tid - kq * 144;      // 0..143
        const int p  = r / 24;              // c-pair 0..5
        const int dq = r - p * 24;          // d-quad 0..23
        const int k0 = kq * 16;

        // preload y: 2 c-rows x 16 k, contiguous in YG0[cl][k]
        float ya[16], yb[16];
        #pragma unroll
        for (int i = 0; i < 4; ++i) {
            const float4 ta = *(const float4*)&YG0[(p * 2 + 0) * 64 + k0 + i * 4];
            const float4 tb = *(const float4*)&YG0[(p * 2 + 1) * 64 + k0 + i * 4];
            ya[i * 4 + 0] = ta.x; ya[i * 4 + 1] = ta.y;
            ya[i * 4 + 2] = ta.z; ya[i * 4 + 3] = ta.w;
            yb[i * 4 + 0] = tb.x; yb[i * 4 + 1] = tb.y;
            yb[i * 4 + 2] = tb.z; yb[i * 4 + 3] = tb.w;
        }

        float a0 = 0, a1 = 0, a2 = 0, a3 = 0, a4 = 0, a5 = 0, a6 = 0, a7 = 0;
        #pragma unroll
        for (int kk = 0; kk < 16; ++kk) {
            const float4 g = *(const float4*)&G1[(k0 + kk) * DIMN + dq * 4];
            const float yx = ya[kk];
            const float yy = yb[kk];
            a0 = fmaf(yx, g.x, a0); a1 = fmaf(yx, g.y, a1);
            a2 = fmaf(yx, g.z, a2); a3 = fmaf(yx, g.w, a3);
            a4 = fmaf(yy, g.x, a4); a5 = fmaf(yy, g.y, a5);
            a6 = fmaf(yy, g.z, a6); a7 = fmaf(yy, g.w, a7);
        }
        float* pa = &pacc[(kq * 144 + r) * 9];
        pa[0] = a0; pa[1] = a1; pa[2] = a2; pa[3] = a3;
        pa[4] = a4; pa[5] = a5; pa[6] = a6; pa[7] = a7;
    }
    __syncthreads();

    // combine 4 k-partials + bias + store (v2's known-good pattern)
    if (tid < 144) {
        const int p  = tid / 24;
        const int dq = tid - p * 24;
        const int c0 = oc * 12 + p * 2;
        const int d0 = dq * 4;

        float s[8];
        #pragma unroll
        for (int j = 0; j < 8; ++j) {
            s[j] = pacc[(0 * 144 + tid) * 9 + j] + pacc[(1 * 144 + tid) * 9 + j]
                 + pacc[(2 * 144 + tid) * 9 + j] + pacc[(3 * 144 + tid) * 9 + j];
        }
        #pragma unroll
        for (int jr = 0; jr < 2; ++jr) {
            int o = (c0 + jr) * DIMN + d0;
            float4 bs = *(const float4*)&bias[o];
            *(float4*)&out[b * NUM_OUT + o] =
                make_float4(s[jr * 4 + 0] + bs.x, s[jr * 4 + 1] + bs.y,
                            s[jr * 4 + 2] + bs.z, s[jr * 4 + 3] + bs.w);
        }
    }
}

// ---------------------------------------------------------------------------
extern "C" void kernel_launch(void* const* d_in, const int* in_sizes, int n_in,
                              void* d_out, int out_size, void* d_ws, size_t ws_size,
                              hipStream_t stream) {
    const float* x        = (const float*)d_in[0];   // (32, 96, 96)
    const float* mus      = (const float*)d_in[1];   // (64, 4)
    const float* log_vars = (const float*)d_in[2];   // (64, 4)
    const float* weights  = (const float*)d_in[3];   // (64,)
    const float* bias     = (const float*)d_in[4];   // (9216,)
    float* out = (float*)d_out;                      // (32, 96, 96)
    float* ws  = (float*)d_ws;

    kA<<<280, 512, 0, stream>>>(x, mus, log_vars, weights, ws);
    kB<<<256, 576, 0, stream>>>(ws, bias, out);
}